// Round 20
// baseline (59.758 us; speedup 1.0000x reference)
//
#include <hip/hip_runtime.h>
#include <hip/hip_bf16.h>
#include <stdint.h>

#define IN_F 4096
#define OUT_F 4096
#define NBKT 512             // 8-row buckets
#define SBLOCKS 410          // 410 * 8192 = 3,358,720 >= NNZ
#define REC_PER_SB 8192
#define SMAX 7168u           // per-bucket cap: mean 6560, sigma 81, +7.5 sigma
#define THRESH 0.01f

typedef unsigned int u32;
typedef unsigned short u16;
typedef __attribute__((ext_vector_type(8))) short short8;   // 8 bf16 = 4 VGPR
typedef __attribute__((ext_vector_type(4))) float f32x4;

// ws layout — offsets DERIVED, 256B-padded
static constexpr size_t pad256(size_t x) { return (x + 255u) & ~(size_t)255u; }
static constexpr size_t WS_XB   = 0;                                           // u16 xB[512][64][8]
static constexpr size_t WS_CUR  = pad256(WS_XB + (size_t)512 * 64 * 8 * 2);    // u32 gcursor[512]
static constexpr size_t WS_BINS = pad256(WS_CUR + (size_t)NBKT * 4);           // u32 sortb[512][SMAX]
static constexpr size_t WS_NEEDED = WS_BINS + (size_t)NBKT * SMAX * 4;

static __device__ __forceinline__ u16 f2bf(float v) {
  __hip_bfloat16 h = __float2bfloat16(v);
  return *reinterpret_cast<u16*>(&h);
}

__global__ __launch_bounds__(512) void k_init(u32* __restrict__ gcursor) {
  gcursor[threadIdx.x] = 0u;
}

// r14-proven 512-bin scatter: fused [blocks 0..31: xB build] + per-block LDS
// counting sort of 8192 COO records + cursor-reserved bucket-major dump.
__global__ __launch_bounds__(1024) void k_scatter(const int* __restrict__ rows,
                                                  const int* __restrict__ cols,
                                                  const float* __restrict__ vals, u32 nnz,
                                                  const float* __restrict__ x,
                                                  u16* __restrict__ xB,
                                                  u32* __restrict__ gcursor,
                                                  u32* __restrict__ sortb) {
  __shared__ u32 cnt[NBKT];
  __shared__ u32 pref[NBKT + 1];
  __shared__ u32 gbase[NBKT];
  __shared__ u32 srt[REC_PER_SB];    // 32 KB
  __shared__ u16 srtb[REC_PER_SB];   // 16 KB (bucket id 0..511)
  const int tid = threadIdx.x;
  const int lane = tid & 63;
  const int wid = tid >> 6;

  // fused xB build: 32 blocks x 1024 threads == 32768 slots (b = g&63, kg = g>>6)
  if (blockIdx.x < 32) {
    const int g = blockIdx.x * 1024 + tid;
    const int b = g & 63;
    const int kg = g >> 6;
    const float* src = x + (size_t)b * IN_F + kg * 8;
    const f32x4 a0 = *reinterpret_cast<const f32x4*>(src);
    const f32x4 a1 = *reinterpret_cast<const f32x4*>(src + 4);
    short8 o;
#pragma unroll
    for (int e = 0; e < 4; ++e) {
      float v = a0[e]; v = (v > THRESH) ? v : 0.0f; o[e] = (short)f2bf(v);
    }
#pragma unroll
    for (int e = 0; e < 4; ++e) {
      float v = a1[e]; v = (v > THRESH) ? v : 0.0f; o[4 + e] = (short)f2bf(v);
    }
    *reinterpret_cast<short8*>(xB + ((size_t)kg * 64 + b) * 8) = o;
  }

  if (tid < NBKT) cnt[tid] = 0;
  __syncthreads();
  const u32 base_i = blockIdx.x * (u32)REC_PER_SB;
  u32 rec[8], bkt[8], rk[8];
#pragma unroll
  for (int j = 0; j < 8; ++j) {
    const u32 i = base_i + (u32)j * 1024u + tid;
    bkt[j] = 0xffffffffu;
    if (i < nnz) {
      const u32 r = (u32)rows[i] & 4095u;
      const u32 c = (u32)cols[i] & 4095u;
      rec[j] = (c << 20) | ((r & 7u) << 16) | (u32)f2bf(vals[i]);
      bkt[j] = r >> 3;
      rk[j] = atomicAdd(&cnt[bkt[j]], 1u);
    }
  }
  __syncthreads();
  // wave-0 exclusive prefix over 512 bins (8 bins/lane + wave scan)
  if (wid == 0) {
    u32 a[8]; u32 s = 0;
#pragma unroll
    for (int j = 0; j < 8; ++j) { a[j] = cnt[lane * 8 + j]; s += a[j]; }
    u32 xx = s;
#pragma unroll
    for (int d = 1; d < 64; d <<= 1) {
      const u32 y = (u32)__shfl_up((int)xx, d, 64);
      if (lane >= d) xx += y;
    }
    u32 e = xx - s;
#pragma unroll
    for (int j = 0; j < 8; ++j) { pref[lane * 8 + j] = e; e += a[j]; }
    if (lane == 63) pref[NBKT] = e;   // block total
  }
  __syncthreads();
  // ranked LDS scatter + per-bucket global reservation
#pragma unroll
  for (int j = 0; j < 8; ++j)
    if (bkt[j] != 0xffffffffu) {
      const u32 pos = pref[bkt[j]] + rk[j];
      srt[pos] = rec[j];
      srtb[pos] = (u16)bkt[j];
    }
  if (tid < NBKT) {
    const u32 len = pref[tid + 1] - pref[tid];
    gbase[tid] = len ? atomicAdd(&gcursor[tid], len) : 0u;
  }
  __syncthreads();
  // run-contiguous dump (~16-record runs)
  const u32 tot = pref[NBKT];
#pragma unroll
  for (int j = 0; j < 8; ++j) {
    const u32 i = (u32)j * 1024u + tid;
    if (i < tot) {
      const u32 t = srtb[i];
      const u32 off = gbase[t] + (i - pref[t]);
      if (off < SMAX) sortb[(size_t)t * SMAX + off] = srt[i];   // +7.5-sigma guard
    }
  }
}

// ONE-PASS accum: 8-row bucket => f32 W[8][4096] = 128 KB LDS holds ALL K.
// Each record read ONCE (coalesced, 4-deep batched -> MLP), no quarter
// predicate, (1024,4) => 128-VGPR budget, no spill (r17 ablation verdict).
// Epilogue axes (r19 bug fixed): D row = (lane>>4)*4+reg = WEIGHT row (A free,
// rows >= 8 are zero -> guard rb<8); D col = lane&15 = BATCH (B free).
__global__ __launch_bounds__(1024, 4) void k_accum(const u32* __restrict__ sortb,
                                                   const u32* __restrict__ ntot,
                                                   const u16* __restrict__ xB,
                                                   const float* __restrict__ bias,
                                                   float* __restrict__ out) {
  __shared__ float W[8 * 4096];     // 128 KB; reused as reduction scratch at the end
  const int tid = threadIdx.x;
  const int lane = tid & 63;
  const int w = tid >> 6;           // wave 0..15: K-slice [w*256, w*256+256)
  const u32 t = blockIdx.x;         // bucket 0..511
  u32 n = ntot[t];
  if (n > SMAX) n = SMAX;
  const u32* bin = sortb + (size_t)t * SMAX;

  const f32x4 zv = {0.f, 0.f, 0.f, 0.f};
  // zero all 32768 floats: 8 x f32x4 per thread
#pragma unroll
  for (int j = 0; j < 8; ++j)
    *reinterpret_cast<f32x4*>(&W[j * 4096 + tid * 4]) = zv;
  __syncthreads();

  // single-pass densify, 4-deep load batching (independent -> MLP)
#define ADDREC(RC) do {                                                   \
    const u32 rl_ = ((RC) >> 16) & 7u;                                    \
    const u32 cl_ = ((RC) >> 20) ^ (rl_ << 3); /* 8-elem XOR swizzle */   \
    unsafeAtomicAdd(&W[rl_ * 4096u + cl_], __uint_as_float((RC) << 16));  \
  } while (0)
  u32 i = (u32)tid;
  for (; i + 3072u < n; i += 4096u) {
    const u32 r0 = bin[i];
    const u32 r1 = bin[i + 1024u];
    const u32 r2 = bin[i + 2048u];
    const u32 r3 = bin[i + 3072u];
    ADDREC(r0); ADDREC(r1); ADDREC(r2); ADDREC(r3);
  }
  for (; i < n; i += 1024u) { const u32 r0 = bin[i]; ADDREC(r0); }
#undef ADDREC
  __syncthreads();

  // dense MFMA over full K; wave w covers k [w*256, w*256+256)
  f32x4 acc0 = zv, acc1 = zv, acc2 = zv, acc3 = zv;
  const int row = lane & 15;        // A-frag row (weight row) / B-frag col (batch)
  const bool alive = row < 8;       // A rows 8..15 are zero (8-row bucket)
  const int rw = row & 7;
  const int e8 = (lane >> 4) * 8;   // A/B-frag k sub-offset
#pragma unroll
  for (int s = 0; s < 8; ++s) {
    const int klb = w * 256 + s * 32 + e8;                // 8-aligned k
    const int sw = klb ^ (rw << 3);                       // matches write swizzle
    f32x4 wa = *reinterpret_cast<const f32x4*>(&W[rw * 4096 + sw]);
    f32x4 wb = *reinterpret_cast<const f32x4*>(&W[rw * 4096 + (sw + 4)]);
    if (!alive) { wa = zv; wb = zv; }
    short8 af;
#pragma unroll
    for (int e = 0; e < 4; ++e) af[e] = (short)f2bf(wa[e]);
#pragma unroll
    for (int e = 0; e < 4; ++e) af[4 + e] = (short)f2bf(wb[e]);
    const u16* bp = xB + (size_t)(klb >> 3) * 512 + (u32)row * 8;
    const short8 b0 = *reinterpret_cast<const short8*>(bp);
    const short8 b1 = *reinterpret_cast<const short8*>(bp + 128);
    const short8 b2 = *reinterpret_cast<const short8*>(bp + 256);
    const short8 b3 = *reinterpret_cast<const short8*>(bp + 384);
    acc0 = __builtin_amdgcn_mfma_f32_16x16x32_bf16(af, b0, acc0, 0, 0, 0);
    acc1 = __builtin_amdgcn_mfma_f32_16x16x32_bf16(af, b1, acc1, 0, 0, 0);
    acc2 = __builtin_amdgcn_mfma_f32_16x16x32_bf16(af, b2, acc2, 0, 0, 0);
    acc3 = __builtin_amdgcn_mfma_f32_16x16x32_bf16(af, b3, acc3, 0, 0, 0);
  }
  __syncthreads();
  // per-wave C partials: slot[((w*4+g)*8 + wrow)*16 + batch15], wrow = rb+qq < 8
  {
    const int ccol = lane & 15;                 // D col = batch (within group g)
    const int rb = (lane >> 4) * 4;             // D row base = weight row
    if (rb < 8) {                               // weight rows 0..7 only (rb in {0,4})
#pragma unroll
      for (int qq = 0; qq < 4; ++qq) W[((w * 4 + 0) * 8 + rb + qq) * 16 + ccol] = acc0[qq];
#pragma unroll
      for (int qq = 0; qq < 4; ++qq) W[((w * 4 + 1) * 8 + rb + qq) * 16 + ccol] = acc1[qq];
#pragma unroll
      for (int qq = 0; qq < 4; ++qq) W[((w * 4 + 2) * 8 + rb + qq) * 16 + ccol] = acc2[qq];
#pragma unroll
      for (int qq = 0; qq < 4; ++qq) W[((w * 4 + 3) * 8 + rb + qq) * 16 + ccol] = acc3[qq];
    }
  }
  __syncthreads();
  // reduce 16 wave-partials -> out(weight row rl, batch b)
  if (tid < 512) {
    const int rl = tid & 7;
    const int b = tid >> 3;        // 0..63
    float sum = bias[t * 8u + rl];
#pragma unroll
    for (int w2 = 0; w2 < 16; ++w2)
      sum += W[((w2 * 4 + (b >> 4)) * 8 + rl) * 16 + (b & 15)];
    out[(size_t)b * OUT_F + t * 8u + rl] = sum;
  }
}

// ---- fallback path (only if ws too small): correct but slow ----
__global__ __launch_bounds__(256) void k_bias_init(const float* __restrict__ bias,
                                                   float* __restrict__ out) {
  const int i = blockIdx.x * 256 + threadIdx.x;
  if (i < 64 * OUT_F) out[i] = bias[i & (OUT_F - 1)];
}

__global__ __launch_bounds__(256) void k_fallback(const int* __restrict__ rows,
                                                  const int* __restrict__ cols,
                                                  const float* __restrict__ vals,
                                                  const float* __restrict__ x,
                                                  float* __restrict__ out, int nnz) {
  const int gw = (int)(((u32)blockIdx.x * blockDim.x + threadIdx.x) >> 6);
  const int lane = threadIdx.x & 63;
  const int nw = (int)(((u32)gridDim.x * blockDim.x) >> 6);
  for (int i = gw; i < nnz; i += nw) {
    const int r = rows[i];
    const int c = cols[i];
    const float v = vals[i];
    const float xv = x[lane * IN_F + c];
    if (xv > THRESH) atomicAdd(&out[(size_t)lane * OUT_F + r], v * xv);
  }
}

extern "C" void kernel_launch(void* const* d_in, const int* in_sizes, int n_in,
                              void* d_out, int out_size, void* d_ws, size_t ws_size,
                              hipStream_t stream) {
  const float* x = (const float*)d_in[0];
  const int* rows = (const int*)d_in[1];
  const int* cols = (const int*)d_in[2];
  const float* vals = (const float*)d_in[3];
  const float* bias = (const float*)d_in[4];
  float* out = (float*)d_out;
  const int nnz = in_sizes[1];

  if (ws_size >= WS_NEEDED && nnz <= SBLOCKS * REC_PER_SB) {
    u16* xB = (u16*)((char*)d_ws + WS_XB);
    u32* gcursor = (u32*)((char*)d_ws + WS_CUR);
    u32* sortb = (u32*)((char*)d_ws + WS_BINS);
    k_init<<<1, 512, 0, stream>>>(gcursor);
    k_scatter<<<SBLOCKS, 1024, 0, stream>>>(rows, cols, vals, (u32)nnz, x, xB,
                                            gcursor, sortb);
    k_accum<<<NBKT, 1024, 0, stream>>>(sortb, gcursor, xB, bias, out);
  } else {
    k_bias_init<<<(64 * OUT_F + 255) / 256, 256, 0, stream>>>(bias, out);
    k_fallback<<<4096, 256, 0, stream>>>(rows, cols, vals, x, out, nnz);
  }
}